// Round 2
// baseline (1427.560 us; speedup 1.0000x reference)
//
#include <hip/hip_runtime.h>
#include <hip/hip_bf16.h>

#define N_NODES 200000
#define N_EDGES 500000
#define F_IN    165
#define HID     256

// ---------- bf16 helpers (raw ushort, used ONLY for internal h buffer) ----------
static __device__ __forceinline__ float bf16_to_f(unsigned short u) {
    return __uint_as_float(((unsigned)u) << 16);
}
static __device__ __forceinline__ unsigned short f_to_bf16(float f) {
    unsigned u = __float_as_uint(f);
    unsigned r = u + 0x7FFFu + ((u >> 16) & 1u);   // round-to-nearest-even
    return (unsigned short)(r >> 16);
}

// ---------- K1: degree + feature scatter-add (fused) ----------
// 192 threads per edge (3 waves); f<165 active. Coalesced gather of x[src]
// and coalesced f32 atomics into agg[dst].
__global__ void scatter_x_kernel(const float* __restrict__ x,
                                 const int* __restrict__ ei,
                                 float* __restrict__ agg,
                                 float* __restrict__ deg) {
    int idx = blockIdx.x * blockDim.x + threadIdx.x;
    int e = idx / 192;
    int f = idx - e * 192;
    if (e >= N_EDGES) return;
    int s = ei[e];
    int d = ei[N_EDGES + e];
    if (f == 0) atomicAdd(&deg[d], 1.0f);
    if (f < F_IN) atomicAdd(&agg[d * F_IN + f], x[s * F_IN + f]);
}

// ---------- K2: deg -> 1/max(deg,1) in place ----------
__global__ void invdeg_kernel(float* __restrict__ deg) {
    int i = blockIdx.x * blockDim.x + threadIdx.x;
    if (i < N_NODES) deg[i] = 1.0f / fmaxf(deg[i], 1.0f);
}

// ---------- K3: h = relu(x@w1_r + (agg*invdeg)@w1_l + b1), bf16 out ----------
// 64x128 tile, 256 threads, 4x8 accum per thread, BK=16, two K-phases.
#define BM 64
#define BN 128
#define BK 16
__global__ __launch_bounds__(256) void gemm1_kernel(
        const float* __restrict__ x, const float* __restrict__ agg,
        const float* __restrict__ invdeg,
        const float* __restrict__ w_r, const float* __restrict__ w_l,
        const float* __restrict__ b1, unsigned short* __restrict__ h) {
    __shared__ float As[BK][BM + 4];
    __shared__ float Bs[BK][BN + 4];
    const int tid = threadIdx.x;
    const int rowbase = blockIdx.x * BM;
    const int colbase = blockIdx.y * BN;
    const int tx = tid & 15;    // col group: 8 cols
    const int ty = tid >> 4;    // row group: 4 rows

    float acc[4][8];
#pragma unroll
    for (int i = 0; i < 4; ++i)
#pragma unroll
        for (int j = 0; j < 8; ++j) acc[i][j] = 0.0f;

#pragma unroll 1
    for (int phase = 0; phase < 2; ++phase) {
        const float* __restrict__ A = phase ? agg : x;
        const float* __restrict__ W = phase ? w_l : w_r;
#pragma unroll 1
        for (int kb = 0; kb < F_IN; kb += BK) {
            // A tile: 64 rows x 16 k
            {
                int kk = tid & 15;
                int r0 = tid >> 4;
                int k = kb + kk;
#pragma unroll
                for (int i = 0; i < 4; ++i) {
                    int r = r0 + i * 16;
                    float v = 0.0f;
                    if (k < F_IN) {
                        int row = rowbase + r;
                        v = A[row * F_IN + k];
                        if (phase) v *= invdeg[row];
                    }
                    As[kk][r] = v;
                }
            }
            // B tile: 16 k x 128 cols
            {
#pragma unroll
                for (int i = 0; i < 8; ++i) {
                    int l = tid + i * 256;
                    int kk = l >> 7;
                    int c = l & 127;
                    int k = kb + kk;
                    Bs[kk][c] = (k < F_IN) ? W[k * HID + colbase + c] : 0.0f;
                }
            }
            __syncthreads();
#pragma unroll
            for (int kk = 0; kk < BK; ++kk) {
                float a[4], b[8];
#pragma unroll
                for (int i = 0; i < 4; ++i) a[i] = As[kk][ty * 4 + i];
#pragma unroll
                for (int j = 0; j < 8; ++j) b[j] = Bs[kk][tx * 8 + j];
#pragma unroll
                for (int i = 0; i < 4; ++i)
#pragma unroll
                    for (int j = 0; j < 8; ++j) acc[i][j] += a[i] * b[j];
            }
            __syncthreads();
        }
    }
    // epilogue: + bias, relu, bf16 store (internal buffer only)
#pragma unroll
    for (int i = 0; i < 4; ++i) {
        int row = rowbase + ty * 4 + i;
#pragma unroll
        for (int j = 0; j < 8; ++j) {
            int col = colbase + tx * 8 + j;
            float v = fmaxf(acc[i][j] + b1[col], 0.0f);
            h[row * HID + col] = f_to_bf16(v);
        }
    }
}

// ---------- K4: per-row layer-2 projections: tl = h@w2_l, tr = h@w2_r ----------
// one wave per row; lane handles k = lane*4 .. lane*4+3
__global__ __launch_bounds__(256) void l2_row_kernel(
        const unsigned short* __restrict__ h,
        const float* __restrict__ w2l, const float* __restrict__ w2r,
        float* __restrict__ tl, float* __restrict__ tr) {
    int row = blockIdx.x * 4 + (threadIdx.x >> 6);
    int lane = threadIdx.x & 63;
    const unsigned short* hp = h + row * HID + lane * 4;
    ushort4 hv = *(const ushort4*)hp;
    float hf[4] = { bf16_to_f(hv.x), bf16_to_f(hv.y), bf16_to_f(hv.z), bf16_to_f(hv.w) };
    float l0 = 0.f, l1 = 0.f, r0 = 0.f, r1 = 0.f;
#pragma unroll
    for (int j = 0; j < 4; ++j) {
        int k = lane * 4 + j;
        l0 += hf[j] * w2l[k * 2 + 0];
        l1 += hf[j] * w2l[k * 2 + 1];
        r0 += hf[j] * w2r[k * 2 + 0];
        r1 += hf[j] * w2r[k * 2 + 1];
    }
#pragma unroll
    for (int off = 32; off > 0; off >>= 1) {
        l0 += __shfl_down(l0, off);
        l1 += __shfl_down(l1, off);
        r0 += __shfl_down(r0, off);
        r1 += __shfl_down(r1, off);
    }
    if (lane == 0) {
        tl[row * 2 + 0] = l0;
        tl[row * 2 + 1] = l1;
        tr[row * 2 + 0] = r0;
        tr[row * 2 + 1] = r1;
    }
}

// ---------- K5: layer-2 edge scatter (2 floats per edge) ----------
__global__ void scatter_t_kernel(const int* __restrict__ ei,
                                 const float* __restrict__ tl,
                                 float* __restrict__ agg2) {
    int e = blockIdx.x * blockDim.x + threadIdx.x;
    if (e >= N_EDGES) return;
    int s = ei[e];
    int d = ei[N_EDGES + e];
    atomicAdd(&agg2[d * 2 + 0], tl[s * 2 + 0]);
    atomicAdd(&agg2[d * 2 + 1], tl[s * 2 + 1]);
}

// ---------- K6: logits = agg2*invdeg + tr + b2 -> f32 out ----------
__global__ void finalize_kernel(const float* __restrict__ agg2,
                                const float* __restrict__ invdeg,
                                const float* __restrict__ tr,
                                const float* __restrict__ b2,
                                float* __restrict__ out) {
    int i = blockIdx.x * blockDim.x + threadIdx.x;
    if (i >= N_NODES) return;
    float inv = invdeg[i];
    out[i * 2 + 0] = agg2[i * 2 + 0] * inv + tr[i * 2 + 0] + b2[0];
    out[i * 2 + 1] = agg2[i * 2 + 1] * inv + tr[i * 2 + 1] + b2[1];
}

// ---------- K7: edge_index -> f32 passthrough output ----------
__global__ void cast_edges_kernel(const int* __restrict__ ei,
                                  float* __restrict__ out) {
    int i = blockIdx.x * blockDim.x + threadIdx.x;
    if (i < 2 * N_EDGES) out[i] = (float)ei[i];
}

// ---------- workspace layout (bytes from d_ws base) ----------
//   [0, 132000000)            agg1   N*F_IN f32   } zeroed together
//   [132000000, 132800000)    deg    N f32        } (one memset of
//   [132800000, 134400000)    agg2   N*2 f32      }  134.4 MB)
//   [134400000, 136000000)    tl     N*2 f32
//   [136000000, 137600000)    tr     N*2 f32
//   [137600000, 240000000)    h      N*HID bf16
extern "C" void kernel_launch(void* const* d_in, const int* in_sizes, int n_in,
                              void* d_out, int out_size, void* d_ws, size_t ws_size,
                              hipStream_t stream) {
    const float* x    = (const float*)d_in[0];
    const int*   ei   = (const int*)d_in[1];
    const float* w1_l = (const float*)d_in[2];
    const float* w1_r = (const float*)d_in[3];
    const float* b1   = (const float*)d_in[4];
    const float* w2_l = (const float*)d_in[5];
    const float* w2_r = (const float*)d_in[6];
    const float* b2   = (const float*)d_in[7];

    char* ws = (char*)d_ws;
    float* agg1 = (float*)(ws);
    float* deg  = (float*)(ws + 132000000);
    float* agg2 = (float*)(ws + 132800000);
    float* tl   = (float*)(ws + 134400000);
    float* tr   = (float*)(ws + 136000000);
    unsigned short* h = (unsigned short*)(ws + 137600000);

    float* out = (float*)d_out;   // f32: logits [0,400000), edges [400000,1400000)

    // zero accumulators (agg1 | deg | agg2 contiguous)
    hipMemsetAsync(ws, 0, 134400000, stream);

    {   // degree + layer-1 feature scatter
        long long total = (long long)N_EDGES * 192;
        int blocks = (int)((total + 255) / 256);
        scatter_x_kernel<<<blocks, 256, 0, stream>>>(x, ei, agg1, deg);
    }
    invdeg_kernel<<<(N_NODES + 255) / 256, 256, 0, stream>>>(deg);
    {
        dim3 grid(N_NODES / BM, HID / BN);
        gemm1_kernel<<<grid, 256, 0, stream>>>(x, agg1, deg, w1_r, w1_l, b1, h);
    }
    l2_row_kernel<<<N_NODES / 4, 256, 0, stream>>>(h, w2_l, w2_r, tl, tr);
    scatter_t_kernel<<<(N_EDGES + 255) / 256, 256, 0, stream>>>(ei, tl, agg2);
    finalize_kernel<<<(N_NODES + 255) / 256, 256, 0, stream>>>(agg2, deg, tr, b2, out);
    cast_edges_kernel<<<(2 * N_EDGES + 255) / 256, 256, 0, stream>>>(ei, out + 2 * N_NODES);
}

// Round 3
// 843.418 us; speedup vs baseline: 1.6926x; 1.6926x over previous
//
#include <hip/hip_runtime.h>
#include <hip/hip_bf16.h>

#define N_NODES 200000
#define N_EDGES 500000
#define F_IN    165
#define HID     256

typedef float  float4a  __attribute__((ext_vector_type(4), aligned(4)));
typedef float  floatx4  __attribute__((ext_vector_type(4)));
typedef short  short8   __attribute__((ext_vector_type(8)));

// pack 8 f32 -> 8 bf16 (truncation; error irrelevant vs 2% threshold), 1 v_perm per pair
static __device__ __forceinline__ short8 pack8(const float e[8]) {
    union { unsigned u[4]; short8 s; } r;
#pragma unroll
    for (int q = 0; q < 4; ++q)
        r.u[q] = __builtin_amdgcn_perm(__float_as_uint(e[2*q+1]),
                                       __float_as_uint(e[2*q]), 0x07060302u);
    return r.s;
}

// ---------- K1: degree + feature scatter-add (fused) ----------
__global__ void scatter_x_kernel(const float* __restrict__ x,
                                 const int* __restrict__ ei,
                                 float* __restrict__ agg,
                                 float* __restrict__ deg) {
    int idx = blockIdx.x * blockDim.x + threadIdx.x;
    int e = idx / 192;
    int f = idx - e * 192;
    if (e >= N_EDGES) return;
    int s = ei[e];
    int d = ei[N_EDGES + e];
    if (f == 0) atomicAdd(&deg[d], 1.0f);
    if (f < F_IN) atomicAdd(&agg[d * F_IN + f], x[s * F_IN + f]);
}

// ---------- K2: deg -> 1/max(deg,1) ----------
__global__ void invdeg_kernel(float* __restrict__ deg) {
    int i = blockIdx.x * blockDim.x + threadIdx.x;
    if (i < N_NODES) deg[i] = 1.0f / fmaxf(deg[i], 1.0f);
}

// ---------- K3: pack [w1_r(k<165); pad | w1_l; pad] into MFMA B-fragment order ----------
// bfrag index: (((c*16 + j)*64 + lane)*8 + q) ; value = W[kb + quad*8 + q][j*16 + (lane&15)]
// chunks c=0..5 -> w1_r (kb=c*32), c=6..11 -> w1_l. 12*16*64*8 bf16 = 192 KB.
__global__ void prep_bfrag_kernel(const float* __restrict__ w1r,
                                  const float* __restrict__ w1l,
                                  short* __restrict__ bfrag) {
    int gid = blockIdx.x * blockDim.x + threadIdx.x;
    if (gid >= 12 * 16 * 64) return;
    int lane = gid & 63;
    int j = (gid >> 6) & 15;
    int c = gid >> 10;
    int quad = lane >> 4, n = lane & 15;
    const float* w = (c < 6) ? w1r : w1l;
    int kb = (c < 6 ? c : c - 6) * 32;
    int col = j * 16 + n;
    float e[8];
#pragma unroll
    for (int q = 0; q < 8; ++q) {
        int k = kb + quad * 8 + q;
        e[q] = (k < F_IN) ? w[k * HID + col] : 0.0f;
    }
    *(short8*)(bfrag + gid * 8) = pack8(e);
}

// ---------- K4: fused MFMA GEMM + bias + relu + layer-2 projection ----------
// h = relu([x | agg*invdeg] @ [w1_r; w1_l] + b1) computed in-register (never stored);
// epilogue reduces tl = h@w2_l, tr = h@w2_r per row (block spans all 256 cols).
// 512 threads = 8 waves; wave w: rows (w&1)*64, cols (w>>1)*64 of the 128x256 tile.
__global__ __launch_bounds__(512, 2) void gemm_fused_kernel(
        const float* __restrict__ x, const float* __restrict__ agg,
        const float* __restrict__ invdeg, const short* __restrict__ bfrag,
        const float* __restrict__ b1,
        const float* __restrict__ w2l, const float* __restrict__ w2r,
        float* __restrict__ tl, float* __restrict__ tr) {
    __shared__ float tlr[128][4];
    const int tid = threadIdx.x;
    const int w = tid >> 6, lane = tid & 63;
    const int quad = lane >> 4, l15 = lane & 15;
    const int mrow0 = blockIdx.x * 128 + (w & 1) * 64;
    const int jbase = (w >> 1) * 4;     // ntile base; cols (w>>1)*64

    ((float*)tlr)[tid < 512 ? tid : 0] = 0.0f;   // 512 floats, one per thread
    __syncthreads();

    int   rows[4];
    float inv[4];
    bool  rv[4];
#pragma unroll
    for (int i = 0; i < 4; ++i) {
        rows[i] = mrow0 + i * 16 + l15;
        rv[i] = rows[i] < N_NODES;
        inv[i] = rv[i] ? invdeg[rows[i]] : 0.0f;
    }

    floatx4 acc[4][4];
#pragma unroll
    for (int i = 0; i < 4; ++i)
#pragma unroll
        for (int jj = 0; jj < 4; ++jj)
            acc[i][jj] = (floatx4){0.f, 0.f, 0.f, 0.f};

#pragma unroll 2
    for (int c = 0; c < 12; ++c) {
        const float* __restrict__ src = (c < 6) ? x : agg;
        const int kb = (c < 6 ? c : c - 6) * 32;
        const bool partial = (kb == 160);     // k 160..191: only 160..164 valid
        short8 a[4];
#pragma unroll
        for (int i = 0; i < 4; ++i) {
            float e[8];
            if (rv[i]) {
                const float* p = src + (long)rows[i] * F_IN + kb + quad * 8;
                if (!partial) {
                    float4a lo = *(const float4a*)p;
                    float4a hi = *(const float4a*)(p + 4);
                    e[0] = lo.x; e[1] = lo.y; e[2] = lo.z; e[3] = lo.w;
                    e[4] = hi.x; e[5] = hi.y; e[6] = hi.z; e[7] = hi.w;
                } else {
#pragma unroll
                    for (int q = 0; q < 8; ++q) {
                        int k = kb + quad * 8 + q;
                        e[q] = (k < F_IN) ? p[q] : 0.0f;
                    }
                }
                if (c >= 6) {
#pragma unroll
                    for (int q = 0; q < 8; ++q) e[q] *= inv[i];
                }
            } else {
#pragma unroll
                for (int q = 0; q < 8; ++q) e[q] = 0.0f;
            }
            a[i] = pack8(e);
        }
        short8 b[4];
#pragma unroll
        for (int jj = 0; jj < 4; ++jj)
            b[jj] = *(const short8*)(bfrag + (((c * 16) + jbase + jj) * 64 + lane) * 8);
#pragma unroll
        for (int i = 0; i < 4; ++i)
#pragma unroll
            for (int jj = 0; jj < 4; ++jj)
                acc[i][jj] = __builtin_amdgcn_mfma_f32_16x16x32_bf16(a[i], b[jj], acc[i][jj], 0, 0, 0);
    }

    // epilogue: bias+relu, project to 2 classes (l and r), reduce across 16 col-lanes
    float bb[4], wl0[4], wl1[4], wr0[4], wr1[4];
#pragma unroll
    for (int jj = 0; jj < 4; ++jj) {
        int col = (w >> 1) * 64 + jj * 16 + l15;
        bb[jj]  = b1[col];
        wl0[jj] = w2l[col * 2];  wl1[jj] = w2l[col * 2 + 1];
        wr0[jj] = w2r[col * 2];  wr1[jj] = w2r[col * 2 + 1];
    }
#pragma unroll
    for (int i = 0; i < 4; ++i) {
#pragma unroll
        for (int t = 0; t < 4; ++t) {
            float s0 = 0.f, s1 = 0.f, s2 = 0.f, s3 = 0.f;
#pragma unroll
            for (int jj = 0; jj < 4; ++jj) {
                float v = fmaxf(acc[i][jj][t] + bb[jj], 0.0f);
                s0 += v * wl0[jj]; s1 += v * wl1[jj];
                s2 += v * wr0[jj]; s3 += v * wr1[jj];
            }
#pragma unroll
            for (int m = 1; m < 16; m <<= 1) {
                s0 += __shfl_xor(s0, m, 64);
                s1 += __shfl_xor(s1, m, 64);
                s2 += __shfl_xor(s2, m, 64);
                s3 += __shfl_xor(s3, m, 64);
            }
            if (l15 == 0) {
                int rl = (w & 1) * 64 + i * 16 + quad * 4 + t;
                atomicAdd(&tlr[rl][0], s0);
                atomicAdd(&tlr[rl][1], s1);
                atomicAdd(&tlr[rl][2], s2);
                atomicAdd(&tlr[rl][3], s3);
            }
        }
    }
    __syncthreads();
    if (tid < 128) {
        int row = blockIdx.x * 128 + tid;
        if (row < N_NODES) {
            tl[row * 2 + 0] = tlr[tid][0];
            tl[row * 2 + 1] = tlr[tid][1];
            tr[row * 2 + 0] = tlr[tid][2];
            tr[row * 2 + 1] = tlr[tid][3];
        }
    }
}

// ---------- K5: layer-2 edge scatter (2 floats per edge) ----------
__global__ void scatter_t_kernel(const int* __restrict__ ei,
                                 const float* __restrict__ tl,
                                 float* __restrict__ agg2) {
    int e = blockIdx.x * blockDim.x + threadIdx.x;
    if (e >= N_EDGES) return;
    int s = ei[e];
    int d = ei[N_EDGES + e];
    atomicAdd(&agg2[d * 2 + 0], tl[s * 2 + 0]);
    atomicAdd(&agg2[d * 2 + 1], tl[s * 2 + 1]);
}

// ---------- K6: logits = agg2*invdeg + tr + b2 ----------
__global__ void finalize_kernel(const float* __restrict__ agg2,
                                const float* __restrict__ invdeg,
                                const float* __restrict__ tr,
                                const float* __restrict__ b2,
                                float* __restrict__ out) {
    int i = blockIdx.x * blockDim.x + threadIdx.x;
    if (i >= N_NODES) return;
    float inv = invdeg[i];
    out[i * 2 + 0] = agg2[i * 2 + 0] * inv + tr[i * 2 + 0] + b2[0];
    out[i * 2 + 1] = agg2[i * 2 + 1] * inv + tr[i * 2 + 1] + b2[1];
}

// ---------- K7: edge_index -> f32 passthrough ----------
__global__ void cast_edges_kernel(const int* __restrict__ ei,
                                  float* __restrict__ out) {
    int i = blockIdx.x * blockDim.x + threadIdx.x;
    if (i < 2 * N_EDGES) out[i] = (float)ei[i];
}

// ---------- workspace layout (bytes) ----------
//   [0, 132000000)            agg1   N*F_IN f32   } zeroed together (134.4 MB memset)
//   [132000000, 132800000)    deg    N f32        }
//   [132800000, 134400000)    agg2   N*2 f32      }
//   [134400000, 136000000)    tl     N*2 f32   (fully written by gemm epilogue)
//   [136000000, 137600000)    tr     N*2 f32   (fully written by gemm epilogue)
//   [137600000, 137796608)    bfrag  12*16*64*8 bf16 (192 KB, fragment-ordered weights)
extern "C" void kernel_launch(void* const* d_in, const int* in_sizes, int n_in,
                              void* d_out, int out_size, void* d_ws, size_t ws_size,
                              hipStream_t stream) {
    const float* x    = (const float*)d_in[0];
    const int*   ei   = (const int*)d_in[1];
    const float* w1_l = (const float*)d_in[2];
    const float* w1_r = (const float*)d_in[3];
    const float* b1   = (const float*)d_in[4];
    const float* w2_l = (const float*)d_in[5];
    const float* w2_r = (const float*)d_in[6];
    const float* b2   = (const float*)d_in[7];

    char* ws = (char*)d_ws;
    float* agg1 = (float*)(ws);
    float* deg  = (float*)(ws + 132000000);
    float* agg2 = (float*)(ws + 132800000);
    float* tl   = (float*)(ws + 134400000);
    float* tr   = (float*)(ws + 136000000);
    short* bfrag = (short*)(ws + 137600000);

    float* out = (float*)d_out;   // f32: logits [0,400000), edges [400000,1400000)

    hipMemsetAsync(ws, 0, 134400000, stream);   // agg1 | deg | agg2

    prep_bfrag_kernel<<<48, 256, 0, stream>>>(w1_r, w1_l, bfrag);
    {
        long long total = (long long)N_EDGES * 192;
        int blocks = (int)((total + 255) / 256);
        scatter_x_kernel<<<blocks, 256, 0, stream>>>(x, ei, agg1, deg);
    }
    invdeg_kernel<<<(N_NODES + 255) / 256, 256, 0, stream>>>(deg);
    {
        int grid = (N_NODES + 127) / 128;   // 1563
        gemm_fused_kernel<<<grid, 512, 0, stream>>>(x, agg1, deg, bfrag, b1, w2_l, w2_r, tl, tr);
    }
    scatter_t_kernel<<<(N_EDGES + 255) / 256, 256, 0, stream>>>(ei, tl, agg2);
    finalize_kernel<<<(N_NODES + 255) / 256, 256, 0, stream>>>(agg2, deg, tr, b2, out);
    cast_edges_kernel<<<(2 * N_EDGES + 255) / 256, 256, 0, stream>>>(ei, out + 2 * N_NODES);
}

// Round 5
// 624.269 us; speedup vs baseline: 2.2868x; 1.3511x over previous
//
#include <hip/hip_runtime.h>
#include <hip/hip_bf16.h>
#include <hip/hip_fp16.h>

#define N_NODES 200000
#define N_EDGES 500000
#define F_IN    165
#define HID     256
#define SX      192   // padded f16 row stride (16B-aligned rows, covers K-chunks)

typedef float    floatx4 __attribute__((ext_vector_type(4)));
typedef float    floatx4a __attribute__((ext_vector_type(4), aligned(16)));
typedef _Float16 half8   __attribute__((ext_vector_type(8)));

// packed f16x2 atomic add (global_atomic_pk_add_f16).
// NOTE: select on __HIP_DEVICE_COMPILE__ — the builtin only exists in the
// device pass; the host pass must still parse this body (never executes).
static __device__ __forceinline__ void atomic_pk_add(__half2* p, __half2 v) {
#if defined(__HIP_DEVICE_COMPILE__)
    typedef _Float16 v2h __attribute__((ext_vector_type(2)));
    __builtin_amdgcn_global_atomic_fadd_v2f16(
        (__attribute__((address_space(1))) v2h*)p, *(v2h*)&v);
#endif
}

// ---------- K0: x (f32, stride 165) -> xh (f16, stride 192, zero-padded) ----------
__global__ void cast_x_kernel(const float* __restrict__ x, _Float16* __restrict__ xh) {
    int idx = blockIdx.x * blockDim.x + threadIdx.x;     // < N*SX = 38.4M
    int row = idx / SX;
    int f = idx - row * SX;
    float v = (f < F_IN) ? x[row * F_IN + f] : 0.0f;
    xh[idx] = (_Float16)v;
}

// ---------- K1: degree + f16 feature scatter-add ----------
// 96 threads/edge; p<83 do one half2 atomic (2 features), p==83 does degree.
__global__ void scatter_x_kernel(const _Float16* __restrict__ xh,
                                 const int* __restrict__ ei,
                                 __half2* __restrict__ aggh,
                                 float* __restrict__ deg) {
    int idx = blockIdx.x * blockDim.x + threadIdx.x;
    int e = idx / 96;
    int p = idx - e * 96;
    if (e >= N_EDGES) return;
    int s = ei[e];
    int d = ei[N_EDGES + e];
    if (p == 83) atomicAdd(&deg[d], 1.0f);
    if (p < 83) {
        __half2 v = ((const __half2*)(xh + (long)s * SX))[p];
        atomic_pk_add(aggh + (long)d * (SX / 2) + p, v);
    }
}

// ---------- K2: deg -> 1/max(deg,1) ----------
__global__ void invdeg_kernel(float* __restrict__ deg) {
    int i = blockIdx.x * blockDim.x + threadIdx.x;
    if (i < N_NODES) deg[i] = 1.0f / fmaxf(deg[i], 1.0f);
}

// ---------- K3: pack [w1_l | w1_r] (f16) into MFMA B-fragment order ----------
// chunk c=0..5 -> w1_l (agg phase), c=6..11 -> w1_r (x phase); kb=(c%6)*32.
// bfrag[(((c*16 + j)*64 + lane)*8 + q)] = W[kb + (lane>>4)*8 + q][j*16 + (lane&15)]
__global__ void prep_bfrag_kernel(const float* __restrict__ w1l,
                                  const float* __restrict__ w1r,
                                  _Float16* __restrict__ bfrag) {
    int gid = blockIdx.x * blockDim.x + threadIdx.x;
    if (gid >= 12 * 16 * 64) return;
    int lane = gid & 63;
    int j = (gid >> 6) & 15;
    int c = gid >> 10;
    int quad = lane >> 4, n = lane & 15;
    const float* w = (c < 6) ? w1l : w1r;
    int kb = (c < 6 ? c : c - 6) * 32;
    int col = j * 16 + n;
    half8 r;
#pragma unroll
    for (int q = 0; q < 8; ++q) {
        int k = kb + quad * 8 + q;
        r[q] = (_Float16)((k < F_IN) ? w[k * HID + col] : 0.0f);
    }
    *(half8*)(bfrag + gid * 8) = r;
}

// ---------- K4: fused MFMA GEMM + invdeg + bias + relu + layer-2 projection ----------
// acc = aggh@w1_l ; acc *= invdeg (per row) ; acc += xh@w1_r ; h=relu(acc+b1) in-register;
// epilogue reduces tl=h@w2_l, tr=h@w2_r per row. 512 thr = 8 waves (2 row x 4 col tiles).
__global__ __launch_bounds__(512, 2) void gemm_fused_kernel(
        const _Float16* __restrict__ xh, const _Float16* __restrict__ aggh,
        const float* __restrict__ invdeg, const _Float16* __restrict__ bfrag,
        const float* __restrict__ b1,
        const float* __restrict__ w2l, const float* __restrict__ w2r,
        float* __restrict__ tl, float* __restrict__ tr) {
    __shared__ float tlr[128][4];
    const int tid = threadIdx.x;
    const int w = tid >> 6, lane = tid & 63;
    const int quad = lane >> 4, l15 = lane & 15;
    const int mrow0 = blockIdx.x * 128 + (w & 1) * 64;
    const int jbase = (w >> 1) * 4;

    ((float*)tlr)[tid < 512 ? tid : 0] = 0.0f;
    __syncthreads();

    int  rows[4];
    bool rv[4];
#pragma unroll
    for (int i = 0; i < 4; ++i) {
        rows[i] = mrow0 + i * 16 + l15;
        rv[i] = rows[i] < N_NODES;
    }

    floatx4 acc[4][4];
#pragma unroll
    for (int i = 0; i < 4; ++i)
#pragma unroll
        for (int jj = 0; jj < 4; ++jj)
            acc[i][jj] = (floatx4){0.f, 0.f, 0.f, 0.f};

    const half8 zero8 = {0, 0, 0, 0, 0, 0, 0, 0};

#pragma unroll 2
    for (int c = 0; c < 12; ++c) {
        const _Float16* __restrict__ src = (c < 6) ? aggh : xh;
        const int kb = (c < 6 ? c : c - 6) * 32;
        half8 a[4], b[4];
#pragma unroll
        for (int i = 0; i < 4; ++i)
            a[i] = rv[i] ? *(const half8*)(src + (long)rows[i] * SX + kb + quad * 8)
                         : zero8;
#pragma unroll
        for (int jj = 0; jj < 4; ++jj)
            b[jj] = *(const half8*)(bfrag + (((c * 16) + jbase + jj) * 64 + lane) * 8);
#pragma unroll
        for (int i = 0; i < 4; ++i)
#pragma unroll
            for (int jj = 0; jj < 4; ++jj)
                acc[i][jj] = __builtin_amdgcn_mfma_f32_16x16x32_f16(a[i], b[jj], acc[i][jj], 0, 0, 0);

        if (c == 5) {
            // scale accumulator rows by invdeg: C-layout row = i*16 + quad*4 + t
#pragma unroll
            for (int i = 0; i < 4; ++i) {
                int rb = mrow0 + i * 16 + quad * 4;
                floatx4 iv;
                if (rb + 3 < N_NODES) {
                    iv = *(const floatx4a*)(invdeg + rb);
                } else {
#pragma unroll
                    for (int t = 0; t < 4; ++t)
                        iv[t] = (rb + t < N_NODES) ? invdeg[rb + t] : 0.0f;
                }
#pragma unroll
                for (int jj = 0; jj < 4; ++jj)
                    acc[i][jj] *= iv;
            }
        }
    }

    // epilogue: bias+relu, project to 2 classes (l and r), reduce across 16 col-lanes
    float bb[4], wl0[4], wl1[4], wr0[4], wr1[4];
#pragma unroll
    for (int jj = 0; jj < 4; ++jj) {
        int col = (w >> 1) * 64 + jj * 16 + l15;
        bb[jj]  = b1[col];
        wl0[jj] = w2l[col * 2];  wl1[jj] = w2l[col * 2 + 1];
        wr0[jj] = w2r[col * 2];  wr1[jj] = w2r[col * 2 + 1];
    }
#pragma unroll
    for (int i = 0; i < 4; ++i) {
#pragma unroll
        for (int t = 0; t < 4; ++t) {
            float s0 = 0.f, s1 = 0.f, s2 = 0.f, s3 = 0.f;
#pragma unroll
            for (int jj = 0; jj < 4; ++jj) {
                float v = fmaxf(acc[i][jj][t] + bb[jj], 0.0f);
                s0 += v * wl0[jj]; s1 += v * wl1[jj];
                s2 += v * wr0[jj]; s3 += v * wr1[jj];
            }
#pragma unroll
            for (int m = 1; m < 16; m <<= 1) {
                s0 += __shfl_xor(s0, m, 64);
                s1 += __shfl_xor(s1, m, 64);
                s2 += __shfl_xor(s2, m, 64);
                s3 += __shfl_xor(s3, m, 64);
            }
            if (l15 == 0) {
                int rl = (w & 1) * 64 + i * 16 + quad * 4 + t;
                atomicAdd(&tlr[rl][0], s0);
                atomicAdd(&tlr[rl][1], s1);
                atomicAdd(&tlr[rl][2], s2);
                atomicAdd(&tlr[rl][3], s3);
            }
        }
    }
    __syncthreads();
    if (tid < 128) {
        int row = blockIdx.x * 128 + tid;
        if (row < N_NODES) {
            tl[row * 2 + 0] = tlr[tid][0];
            tl[row * 2 + 1] = tlr[tid][1];
            tr[row * 2 + 0] = tlr[tid][2];
            tr[row * 2 + 1] = tlr[tid][3];
        }
    }
}

// ---------- K5: layer-2 edge scatter (2 f32 atomics per edge) ----------
__global__ void scatter_t_kernel(const int* __restrict__ ei,
                                 const float* __restrict__ tl,
                                 float* __restrict__ agg2) {
    int e = blockIdx.x * blockDim.x + threadIdx.x;
    if (e >= N_EDGES) return;
    int s = ei[e];
    int d = ei[N_EDGES + e];
    atomicAdd(&agg2[d * 2 + 0], tl[s * 2 + 0]);
    atomicAdd(&agg2[d * 2 + 1], tl[s * 2 + 1]);
}

// ---------- K6: logits = agg2*invdeg + tr + b2 ----------
__global__ void finalize_kernel(const float* __restrict__ agg2,
                                const float* __restrict__ invdeg,
                                const float* __restrict__ tr,
                                const float* __restrict__ b2,
                                float* __restrict__ out) {
    int i = blockIdx.x * blockDim.x + threadIdx.x;
    if (i >= N_NODES) return;
    float inv = invdeg[i];
    out[i * 2 + 0] = agg2[i * 2 + 0] * inv + tr[i * 2 + 0] + b2[0];
    out[i * 2 + 1] = agg2[i * 2 + 1] * inv + tr[i * 2 + 1] + b2[1];
}

// ---------- K7: edge_index -> f32 passthrough ----------
__global__ void cast_edges_kernel(const int* __restrict__ ei,
                                  float* __restrict__ out) {
    int i = blockIdx.x * blockDim.x + threadIdx.x;
    if (i < 2 * N_EDGES) out[i] = (float)ei[i];
}

// ---------- workspace layout (bytes) ----------
//   [0, 76800000)             aggh   N*SX f16     } zeroed together (79.2 MB memset)
//   [76800000, 77600000)      deg    N f32        }
//   [77600000, 79200000)      agg2   N*2 f32      }
//   [79200000, 80800000)      tl     N*2 f32
//   [80800000, 82400000)      tr     N*2 f32
//   [82400000, 82596608)      bfrag  12*16*64*8 f16 (192 KB)
//   [82600000, 159400000)     xh     N*SX f16 (fully written by cast_x)
extern "C" void kernel_launch(void* const* d_in, const int* in_sizes, int n_in,
                              void* d_out, int out_size, void* d_ws, size_t ws_size,
                              hipStream_t stream) {
    const float* x    = (const float*)d_in[0];
    const int*   ei   = (const int*)d_in[1];
    const float* w1_l = (const float*)d_in[2];
    const float* w1_r = (const float*)d_in[3];
    const float* b1   = (const float*)d_in[4];
    const float* w2_l = (const float*)d_in[5];
    const float* w2_r = (const float*)d_in[6];
    const float* b2   = (const float*)d_in[7];

    char* ws = (char*)d_ws;
    _Float16* aggh = (_Float16*)(ws);
    float* deg  = (float*)(ws + 76800000);
    float* agg2 = (float*)(ws + 77600000);
    float* tl   = (float*)(ws + 79200000);
    float* tr   = (float*)(ws + 80800000);
    _Float16* bfrag = (_Float16*)(ws + 82400000);
    _Float16* xh = (_Float16*)(ws + 82600000);

    float* out = (float*)d_out;   // f32: logits [0,400000), edges [400000,1400000)

    (void)hipMemsetAsync(ws, 0, 79200000, stream);   // aggh | deg | agg2

    cast_x_kernel<<<(N_NODES * SX) / 256, 256, 0, stream>>>(x, xh);
    prep_bfrag_kernel<<<48, 256, 0, stream>>>(w1_l, w1_r, bfrag);
    {
        long long total = (long long)N_EDGES * 96;
        int blocks = (int)((total + 255) / 256);
        scatter_x_kernel<<<blocks, 256, 0, stream>>>(xh, ei, (__half2*)aggh, deg);
    }
    invdeg_kernel<<<(N_NODES + 255) / 256, 256, 0, stream>>>(deg);
    {
        int grid = (N_NODES + 127) / 128;   // 1563
        gemm_fused_kernel<<<grid, 512, 0, stream>>>(xh, aggh, deg, bfrag, b1, w2_l, w2_r, tl, tr);
    }
    scatter_t_kernel<<<(N_EDGES + 255) / 256, 256, 0, stream>>>(ei, tl, agg2);
    finalize_kernel<<<(N_NODES + 255) / 256, 256, 0, stream>>>(agg2, deg, tr, b2, out);
    cast_edges_kernel<<<(2 * N_EDGES + 255) / 256, 256, 0, stream>>>(ei, out + 2 * N_NODES);
}

// Round 6
// 505.854 us; speedup vs baseline: 2.8221x; 1.2341x over previous
//
#include <hip/hip_runtime.h>
#include <hip/hip_bf16.h>
#include <hip/hip_fp16.h>

#define N_NODES 200000
#define N_EDGES 500000
#define F_IN    165
#define HID     256
#define SX      192   // padded f16 row stride (96 half2, 16B-aligned rows)
#define NB      782   // ceil(N_NODES/256) scan blocks

typedef float    floatx4 __attribute__((ext_vector_type(4)));
typedef float    floatx4a __attribute__((ext_vector_type(4), aligned(16)));
typedef _Float16 half8   __attribute__((ext_vector_type(8)));

// ---------- K0: x (f32, stride 165) -> xh (f16 half2, stride 96 pairs) ----------
__global__ void cast_x_kernel(const float* __restrict__ x, __half2* __restrict__ xh) {
    int idx = blockIdx.x * blockDim.x + threadIdx.x;   // < N*96
    int row = idx / 96;
    int p = idx - row * 96;
    int f0 = 2 * p;
    float v0 = (f0 < F_IN) ? x[(long)row * F_IN + f0] : 0.0f;
    float v1 = (f0 + 1 < F_IN) ? x[(long)row * F_IN + f0 + 1] : 0.0f;
    xh[idx] = __floats2half2_rn(v0, v1);
}

// ---------- K1: dst-degree histogram ----------
__global__ void hist_kernel(const int* __restrict__ ei, int* __restrict__ degi) {
    int e = blockIdx.x * blockDim.x + threadIdx.x;
    if (e < N_EDGES) atomicAdd(&degi[ei[N_EDGES + e]], 1);
}

// ---------- K2a: per-block degree sums ----------
__global__ __launch_bounds__(256) void block_sum_kernel(const int* __restrict__ degi,
                                                        int* __restrict__ bsum) {
    __shared__ int sh[256];
    int t = threadIdx.x, i = blockIdx.x * 256 + t;
    sh[t] = (i < N_NODES) ? degi[i] : 0;
    __syncthreads();
#pragma unroll
    for (int off = 128; off > 0; off >>= 1) {
        if (t < off) sh[t] += sh[t + off];
        __syncthreads();
    }
    if (t == 0) bsum[blockIdx.x] = sh[0];
}

// ---------- K2b: scan the 782 block sums (1 block) ----------
__global__ __launch_bounds__(1024) void scan_bsum_kernel(const int* __restrict__ bsum,
                                                         int* __restrict__ boff,
                                                         int* __restrict__ row_start) {
    __shared__ int sh[1024];
    int t = threadIdx.x;
    int v = (t < NB) ? bsum[t] : 0;
    sh[t] = v;
    __syncthreads();
    for (int off = 1; off < 1024; off <<= 1) {
        int u = (t >= off) ? sh[t - off] : 0;
        __syncthreads();
        sh[t] += u;
        __syncthreads();
    }
    if (t < NB) boff[t] = sh[t] - v;               // exclusive
    if (t == 1023) row_start[N_NODES] = sh[1023];  // total = E
}

// ---------- K2c: emit row_start / cursor / invdeg ----------
__global__ __launch_bounds__(256) void scan_emit_kernel(const int* __restrict__ degi,
                                                        const int* __restrict__ boff,
                                                        int* __restrict__ row_start,
                                                        int* __restrict__ cursor,
                                                        float* __restrict__ invdeg) {
    __shared__ int sh[256];
    int t = threadIdx.x, i = blockIdx.x * 256 + t;
    int d = (i < N_NODES) ? degi[i] : 0;
    sh[t] = d;
    __syncthreads();
#pragma unroll
    for (int off = 1; off < 256; off <<= 1) {
        int u = (t >= off) ? sh[t - off] : 0;
        __syncthreads();
        sh[t] += u;
        __syncthreads();
    }
    if (i < N_NODES) {
        int row = boff[blockIdx.x] + sh[t] - d;    // exclusive scan value
        row_start[i] = row;
        cursor[i] = row;
        invdeg[i] = 1.0f / fmaxf((float)d, 1.0f);
    }
}

// ---------- K3: bucket edges into CSR ----------
__global__ void scatter_edges_kernel(const int* __restrict__ ei,
                                     int* __restrict__ cursor,
                                     int* __restrict__ csr) {
    int e = blockIdx.x * blockDim.x + threadIdx.x;
    if (e >= N_EDGES) return;
    int s = ei[e];
    int d = ei[N_EDGES + e];
    int pos = atomicAdd(&cursor[d], 1);
    csr[pos] = s;
}

// ---------- K4: gather-aggregate (NO atomics): aggh[n] = sum xh[src] ----------
__global__ void gather_agg_kernel(const __half2* __restrict__ xh,
                                  const int* __restrict__ row_start,
                                  const int* __restrict__ csr,
                                  __half2* __restrict__ aggh) {
    int idx = blockIdx.x * blockDim.x + threadIdx.x;   // < N*96
    int n = idx / 96;
    int p = idx - n * 96;
    int e0 = row_start[n], e1 = row_start[n + 1];
    float sx = 0.f, sy = 0.f;
    for (int e = e0; e < e1; ++e) {
        int s = csr[e];
        float2 f = __half22float2(xh[(long)s * 96 + p]);
        sx += f.x; sy += f.y;
    }
    aggh[idx] = __floats2half2_rn(sx, sy);
}

// ---------- K5: pack [w1_l | w1_r] (f16) into MFMA B-fragment order ----------
__global__ void prep_bfrag_kernel(const float* __restrict__ w1l,
                                  const float* __restrict__ w1r,
                                  _Float16* __restrict__ bfrag) {
    int gid = blockIdx.x * blockDim.x + threadIdx.x;
    if (gid >= 12 * 16 * 64) return;
    int lane = gid & 63;
    int j = (gid >> 6) & 15;
    int c = gid >> 10;
    int quad = lane >> 4, n = lane & 15;
    const float* w = (c < 6) ? w1l : w1r;
    int kb = (c < 6 ? c : c - 6) * 32;
    int col = j * 16 + n;
    half8 r;
#pragma unroll
    for (int q = 0; q < 8; ++q) {
        int k = kb + quad * 8 + q;
        r[q] = (_Float16)((k < F_IN) ? w[k * HID + col] : 0.0f);
    }
    *(half8*)(bfrag + gid * 8) = r;
}

// ---------- K6: fused MFMA GEMM + invdeg + bias + relu + layer-2 projection ----------
__global__ __launch_bounds__(512, 2) void gemm_fused_kernel(
        const _Float16* __restrict__ xh, const _Float16* __restrict__ aggh,
        const float* __restrict__ invdeg, const _Float16* __restrict__ bfrag,
        const float* __restrict__ b1,
        const float* __restrict__ w2l, const float* __restrict__ w2r,
        float* __restrict__ tl, float* __restrict__ tr) {
    __shared__ float tlr[128][4];
    const int tid = threadIdx.x;
    const int w = tid >> 6, lane = tid & 63;
    const int quad = lane >> 4, l15 = lane & 15;
    const int mrow0 = blockIdx.x * 128 + (w & 1) * 64;
    const int jbase = (w >> 1) * 4;

    ((float*)tlr)[tid < 512 ? tid : 0] = 0.0f;
    __syncthreads();

    int  rows[4];
    bool rv[4];
#pragma unroll
    for (int i = 0; i < 4; ++i) {
        rows[i] = mrow0 + i * 16 + l15;
        rv[i] = rows[i] < N_NODES;
    }

    floatx4 acc[4][4];
#pragma unroll
    for (int i = 0; i < 4; ++i)
#pragma unroll
        for (int jj = 0; jj < 4; ++jj)
            acc[i][jj] = (floatx4){0.f, 0.f, 0.f, 0.f};

    const half8 zero8 = {0, 0, 0, 0, 0, 0, 0, 0};

#pragma unroll 2
    for (int c = 0; c < 12; ++c) {
        const _Float16* __restrict__ src = (c < 6) ? aggh : xh;
        const int kb = (c < 6 ? c : c - 6) * 32;
        half8 a[4], b[4];
#pragma unroll
        for (int i = 0; i < 4; ++i)
            a[i] = rv[i] ? *(const half8*)(src + (long)rows[i] * SX + kb + quad * 8)
                         : zero8;
#pragma unroll
        for (int jj = 0; jj < 4; ++jj)
            b[jj] = *(const half8*)(bfrag + (((c * 16) + jbase + jj) * 64 + lane) * 8);
#pragma unroll
        for (int i = 0; i < 4; ++i)
#pragma unroll
            for (int jj = 0; jj < 4; ++jj)
                acc[i][jj] = __builtin_amdgcn_mfma_f32_16x16x32_f16(a[i], b[jj], acc[i][jj], 0, 0, 0);

        if (c == 5) {   // scale agg-phase accumulator rows by invdeg
#pragma unroll
            for (int i = 0; i < 4; ++i) {
                int rb = mrow0 + i * 16 + quad * 4;
                floatx4 iv;
                if (rb + 3 < N_NODES) {
                    iv = *(const floatx4a*)(invdeg + rb);
                } else {
#pragma unroll
                    for (int t = 0; t < 4; ++t)
                        iv[t] = (rb + t < N_NODES) ? invdeg[rb + t] : 0.0f;
                }
#pragma unroll
                for (int jj = 0; jj < 4; ++jj)
                    acc[i][jj] *= iv;
            }
        }
    }

    float bb[4], wl0[4], wl1[4], wr0[4], wr1[4];
#pragma unroll
    for (int jj = 0; jj < 4; ++jj) {
        int col = (w >> 1) * 64 + jj * 16 + l15;
        bb[jj]  = b1[col];
        wl0[jj] = w2l[col * 2];  wl1[jj] = w2l[col * 2 + 1];
        wr0[jj] = w2r[col * 2];  wr1[jj] = w2r[col * 2 + 1];
    }
#pragma unroll
    for (int i = 0; i < 4; ++i) {
#pragma unroll
        for (int t = 0; t < 4; ++t) {
            float s0 = 0.f, s1 = 0.f, s2 = 0.f, s3 = 0.f;
#pragma unroll
            for (int jj = 0; jj < 4; ++jj) {
                float v = fmaxf(acc[i][jj][t] + bb[jj], 0.0f);
                s0 += v * wl0[jj]; s1 += v * wl1[jj];
                s2 += v * wr0[jj]; s3 += v * wr1[jj];
            }
#pragma unroll
            for (int m = 1; m < 16; m <<= 1) {
                s0 += __shfl_xor(s0, m, 64);
                s1 += __shfl_xor(s1, m, 64);
                s2 += __shfl_xor(s2, m, 64);
                s3 += __shfl_xor(s3, m, 64);
            }
            if (l15 == 0) {
                int rl = (w & 1) * 64 + i * 16 + quad * 4 + t;
                atomicAdd(&tlr[rl][0], s0);
                atomicAdd(&tlr[rl][1], s1);
                atomicAdd(&tlr[rl][2], s2);
                atomicAdd(&tlr[rl][3], s3);
            }
        }
    }
    __syncthreads();
    if (tid < 128) {
        int row = blockIdx.x * 128 + tid;
        if (row < N_NODES) {
            tl[row * 2 + 0] = tlr[tid][0];
            tl[row * 2 + 1] = tlr[tid][1];
            tr[row * 2 + 0] = tlr[tid][2];
            tr[row * 2 + 1] = tlr[tid][3];
        }
    }
}

// ---------- K7: fused layer-2 gather + finalize (NO atomics) ----------
__global__ void gather_out_kernel(const int* __restrict__ row_start,
                                  const int* __restrict__ csr,
                                  const float* __restrict__ tl,
                                  const float* __restrict__ tr,
                                  const float* __restrict__ invdeg,
                                  const float* __restrict__ b2,
                                  float* __restrict__ out) {
    int i = blockIdx.x * blockDim.x + threadIdx.x;
    if (i >= N_NODES) return;
    int e0 = row_start[i], e1 = row_start[i + 1];
    float a0 = 0.f, a1 = 0.f;
    for (int e = e0; e < e1; ++e) {
        int s = csr[e];
        a0 += tl[s * 2 + 0];
        a1 += tl[s * 2 + 1];
    }
    float inv = invdeg[i];
    out[i * 2 + 0] = a0 * inv + tr[i * 2 + 0] + b2[0];
    out[i * 2 + 1] = a1 * inv + tr[i * 2 + 1] + b2[1];
}

// ---------- K8: edge_index -> f32 passthrough ----------
__global__ void cast_edges_kernel(const int* __restrict__ ei,
                                  float* __restrict__ out) {
    int i = blockIdx.x * blockDim.x + threadIdx.x;
    if (i < 2 * N_EDGES) out[i] = (float)ei[i];
}

// ---------- workspace layout (bytes); ws proven >= 240 MB in round 2 ----------
//   0          degi      800000   (memset 0)
//   800000     row_start 800016   (N+1 ints)
//   1600032    cursor    800000
//   2400032    invdeg    800000
//   3200032    csr       2000000
//   5200032    tl        1600000
//   6800032    tr        1600000
//   8400032    bsum      3200
//   8403232    boff      3200
//   8406432    bfrag     196608
//   8610000    aggh      76800000  (f16, stride SX)
//   85410000   xh        76800000  (f16, stride SX)
//   end 162210000
extern "C" void kernel_launch(void* const* d_in, const int* in_sizes, int n_in,
                              void* d_out, int out_size, void* d_ws, size_t ws_size,
                              hipStream_t stream) {
    const float* x    = (const float*)d_in[0];
    const int*   ei   = (const int*)d_in[1];
    const float* w1_l = (const float*)d_in[2];
    const float* w1_r = (const float*)d_in[3];
    const float* b1   = (const float*)d_in[4];
    const float* w2_l = (const float*)d_in[5];
    const float* w2_r = (const float*)d_in[6];
    const float* b2   = (const float*)d_in[7];

    char* ws = (char*)d_ws;
    int*   degi      = (int*)(ws);
    int*   row_start = (int*)(ws + 800000);
    int*   cursor    = (int*)(ws + 1600032);
    float* invdeg    = (float*)(ws + 2400032);
    int*   csr       = (int*)(ws + 3200032);
    float* tl        = (float*)(ws + 5200032);
    float* tr        = (float*)(ws + 6800032);
    int*   bsum      = (int*)(ws + 8400032);
    int*   boff      = (int*)(ws + 8403232);
    _Float16* bfrag  = (_Float16*)(ws + 8406432);
    _Float16* aggh   = (_Float16*)(ws + 8610000);
    _Float16* xh     = (_Float16*)(ws + 85410000);

    float* out = (float*)d_out;   // f32: logits [0,400000), edges [400000,1400000)

    (void)hipMemsetAsync(degi, 0, 800000, stream);

    cast_x_kernel<<<75000, 256, 0, stream>>>(x, (__half2*)xh);
    prep_bfrag_kernel<<<48, 256, 0, stream>>>(w1_l, w1_r, bfrag);

    hist_kernel<<<(N_EDGES + 255) / 256, 256, 0, stream>>>(ei, degi);
    block_sum_kernel<<<NB, 256, 0, stream>>>(degi, bsum);
    scan_bsum_kernel<<<1, 1024, 0, stream>>>(bsum, boff, row_start);
    scan_emit_kernel<<<NB, 256, 0, stream>>>(degi, boff, row_start, cursor, invdeg);
    scatter_edges_kernel<<<(N_EDGES + 255) / 256, 256, 0, stream>>>(ei, cursor, csr);

    gather_agg_kernel<<<75000, 256, 0, stream>>>((const __half2*)xh, row_start, csr,
                                                 (__half2*)aggh);

    gemm_fused_kernel<<<(N_NODES + 127) / 128, 512, 0, stream>>>(
        xh, aggh, invdeg, bfrag, b1, w2_l, w2_r, tl, tr);

    gather_out_kernel<<<NB, 256, 0, stream>>>(row_start, csr, tl, tr, invdeg, b2, out);
    cast_edges_kernel<<<(2 * N_EDGES + 255) / 256, 256, 0, stream>>>(ei, out + 2 * N_NODES);
}

// Round 7
// 483.664 us; speedup vs baseline: 2.9516x; 1.0459x over previous
//
#include <hip/hip_runtime.h>
#include <hip/hip_bf16.h>
#include <hip/hip_fp16.h>

#define N_NODES 200000
#define N_EDGES 500000
#define F_IN    165
#define HID     256
#define SX      192   // padded f16 row stride (96 half2, 16B-aligned rows)
#define NB      782   // ceil(N_NODES/256) scan blocks

typedef float    floatx4 __attribute__((ext_vector_type(4)));
typedef float    floatx4a __attribute__((ext_vector_type(4), aligned(16)));
typedef _Float16 half8   __attribute__((ext_vector_type(8)));

// ---------- K0: x (f32, stride 165) -> xh (f16 half2, stride 96 pairs) ----------
__global__ void cast_x_kernel(const float* __restrict__ x, __half2* __restrict__ xh) {
    int idx = blockIdx.x * blockDim.x + threadIdx.x;   // < N*96
    int row = idx / 96;
    int p = idx - row * 96;
    int f0 = 2 * p;
    float v0 = (f0 < F_IN) ? x[(long)row * F_IN + f0] : 0.0f;
    float v1 = (f0 + 1 < F_IN) ? x[(long)row * F_IN + f0 + 1] : 0.0f;
    xh[idx] = __floats2half2_rn(v0, v1);
}

// ---------- K1: dst-degree histogram ----------
__global__ void hist_kernel(const int* __restrict__ ei, int* __restrict__ degi) {
    int e = blockIdx.x * blockDim.x + threadIdx.x;
    if (e < N_EDGES) atomicAdd(&degi[ei[N_EDGES + e]], 1);
}

// ---------- K2a: per-block degree sums ----------
__global__ __launch_bounds__(256) void block_sum_kernel(const int* __restrict__ degi,
                                                        int* __restrict__ bsum) {
    __shared__ int sh[256];
    int t = threadIdx.x, i = blockIdx.x * 256 + t;
    sh[t] = (i < N_NODES) ? degi[i] : 0;
    __syncthreads();
#pragma unroll
    for (int off = 128; off > 0; off >>= 1) {
        if (t < off) sh[t] += sh[t + off];
        __syncthreads();
    }
    if (t == 0) bsum[blockIdx.x] = sh[0];
}

// ---------- K2b: scan the 782 block sums (1 block) ----------
__global__ __launch_bounds__(1024) void scan_bsum_kernel(const int* __restrict__ bsum,
                                                         int* __restrict__ boff,
                                                         int* __restrict__ row_start) {
    __shared__ int sh[1024];
    int t = threadIdx.x;
    int v = (t < NB) ? bsum[t] : 0;
    sh[t] = v;
    __syncthreads();
    for (int off = 1; off < 1024; off <<= 1) {
        int u = (t >= off) ? sh[t - off] : 0;
        __syncthreads();
        sh[t] += u;
        __syncthreads();
    }
    if (t < NB) boff[t] = sh[t] - v;               // exclusive
    if (t == 1023) row_start[N_NODES] = sh[1023];  // total = E
}

// ---------- K2c: emit row_start / cursor / invdeg ----------
__global__ __launch_bounds__(256) void scan_emit_kernel(const int* __restrict__ degi,
                                                        const int* __restrict__ boff,
                                                        int* __restrict__ row_start,
                                                        int* __restrict__ cursor,
                                                        float* __restrict__ invdeg) {
    __shared__ int sh[256];
    int t = threadIdx.x, i = blockIdx.x * 256 + t;
    int d = (i < N_NODES) ? degi[i] : 0;
    sh[t] = d;
    __syncthreads();
#pragma unroll
    for (int off = 1; off < 256; off <<= 1) {
        int u = (t >= off) ? sh[t - off] : 0;
        __syncthreads();
        sh[t] += u;
        __syncthreads();
    }
    if (i < N_NODES) {
        int row = boff[blockIdx.x] + sh[t] - d;    // exclusive scan value
        row_start[i] = row;
        cursor[i] = row;
        invdeg[i] = 1.0f / fmaxf((float)d, 1.0f);
    }
}

// ---------- K3: bucket edges into CSR ----------
__global__ void scatter_edges_kernel(const int* __restrict__ ei,
                                     int* __restrict__ cursor,
                                     int* __restrict__ csr) {
    int e = blockIdx.x * blockDim.x + threadIdx.x;
    if (e >= N_EDGES) return;
    int s = ei[e];
    int d = ei[N_EDGES + e];
    int pos = atomicAdd(&cursor[d], 1);
    csr[pos] = s;
}

// ---------- K4: gather-aggregate (NO atomics): aggh[n] = sum xh[src] ----------
__global__ void gather_agg_kernel(const __half2* __restrict__ xh,
                                  const int* __restrict__ row_start,
                                  const int* __restrict__ csr,
                                  __half2* __restrict__ aggh) {
    int idx = blockIdx.x * blockDim.x + threadIdx.x;   // < N*96
    int n = idx / 96;
    int p = idx - n * 96;
    int e0 = row_start[n], e1 = row_start[n + 1];
    float sx = 0.f, sy = 0.f;
    for (int e = e0; e < e1; ++e) {
        int s = csr[e];
        float2 f = __half22float2(xh[(long)s * 96 + p]);
        sx += f.x; sy += f.y;
    }
    aggh[idx] = __floats2half2_rn(sx, sy);
}

// ---------- K5: pack [w1_l | w1_r] (f16) into MFMA B-fragment order ----------
__global__ void prep_bfrag_kernel(const float* __restrict__ w1l,
                                  const float* __restrict__ w1r,
                                  _Float16* __restrict__ bfrag) {
    int gid = blockIdx.x * blockDim.x + threadIdx.x;
    if (gid >= 12 * 16 * 64) return;
    int lane = gid & 63;
    int j = (gid >> 6) & 15;
    int c = gid >> 10;
    int quad = lane >> 4, n = lane & 15;
    const float* w = (c < 6) ? w1l : w1r;
    int kb = (c < 6 ? c : c - 6) * 32;
    int col = j * 16 + n;
    half8 r;
#pragma unroll
    for (int q = 0; q < 8; ++q) {
        int k = kb + quad * 8 + q;
        r[q] = (_Float16)((k < F_IN) ? w[k * HID + col] : 0.0f);
    }
    *(half8*)(bfrag + gid * 8) = r;
}

// ---------- K6: fused MFMA GEMM + invdeg + bias + relu + layer-2 projection ----------
// A-tile staged through LDS via global_load_lds width=16 (each A byte enters CU once).
// XOR-swizzled LDS layout: slot(r,q) = r*4 + (q ^ ((r>>1)&3)); DMA stays lane-contiguous
// (slot t written by thread t), ds_read_b128 reads hit <=2-way banks (free).
__global__ __launch_bounds__(512, 2) void gemm_fused_kernel(
        const _Float16* __restrict__ xh, const _Float16* __restrict__ aggh,
        const float* __restrict__ invdeg, const _Float16* __restrict__ bfrag,
        const float* __restrict__ b1,
        const float* __restrict__ w2l, const float* __restrict__ w2r,
        float* __restrict__ tl, float* __restrict__ tr) {
    __shared__ __attribute__((aligned(16))) _Float16 As[2][128 * 32];  // 2 x 8KB
    __shared__ float tlr[128][4];
    const int tid = threadIdx.x;
    const int w = tid >> 6, lane = tid & 63;
    const int quad = lane >> 4, l15 = lane & 15;
    const int rowbase = blockIdx.x * 128;
    const int mrow0 = rowbase + (w & 1) * 64;
    const int rhalf = (w & 1) * 64;
    const int jbase = (w >> 1) * 4;

    ((float*)tlr)[tid < 512 ? tid : 0] = 0.0f;

    // staging address (fixed per thread): row_l = tid>>2, sidx = tid&3,
    // fetched seg = sidx ^ ((row_l>>1)&3); clamp row to stay in-buffer.
    const int srow_l = tid >> 2;
    const int sseg = (tid & 3) ^ ((srow_l >> 1) & 3);
    int srow = rowbase + srow_l;
    if (srow >= N_NODES) srow = N_NODES - 1;
    const long sgoff = (long)srow * SX + sseg * 8;

    floatx4 acc[4][4];
#pragma unroll
    for (int i = 0; i < 4; ++i)
#pragma unroll
        for (int jj = 0; jj < 4; ++jj)
            acc[i][jj] = (floatx4){0.f, 0.f, 0.f, 0.f};

    __syncthreads();

#pragma unroll 1
    for (int it = 0; it < 6; ++it) {
        // stage chunk pair (2*it, 2*it+1): one 16B DMA per thread per chunk
#pragma unroll
        for (int u = 0; u < 2; ++u) {
            const int cc = it * 2 + u;
            const _Float16* __restrict__ src = (cc < 6) ? aggh : xh;
            const int kb = (cc < 6 ? cc : cc - 6) * 32;
            const _Float16* gp = src + sgoff + kb;
            char* dst = (char*)(&As[u][0]) + (tid & ~63) * 16;  // wave-uniform base
            __builtin_amdgcn_global_load_lds(
                (const __attribute__((address_space(1))) void*)gp,
                (__attribute__((address_space(3))) void*)dst, 16, 0, 0);
        }
        __syncthreads();   // drains the DMA (vmcnt) + orders LDS

#pragma unroll
        for (int u = 0; u < 2; ++u) {
            const int cc = it * 2 + u;
            half8 a[4], b[4];
#pragma unroll
            for (int i = 0; i < 4; ++i) {
                int r = rhalf + i * 16 + l15;
                int slot = r * 4 + (quad ^ ((r >> 1) & 3));
                a[i] = *(const half8*)(&As[u][slot * 8]);
            }
#pragma unroll
            for (int jj = 0; jj < 4; ++jj)
                b[jj] = *(const half8*)(bfrag + (((cc * 16) + jbase + jj) * 64 + lane) * 8);
#pragma unroll
            for (int i = 0; i < 4; ++i)
#pragma unroll
                for (int jj = 0; jj < 4; ++jj)
                    acc[i][jj] = __builtin_amdgcn_mfma_f32_16x16x32_f16(a[i], b[jj], acc[i][jj], 0, 0, 0);

            if (cc == 5) {   // agg phase done: scale accumulator rows by invdeg
#pragma unroll
                for (int i = 0; i < 4; ++i) {
                    int rb = mrow0 + i * 16 + quad * 4;
                    floatx4 iv;
                    if (rb + 3 < N_NODES) {
                        iv = *(const floatx4a*)(invdeg + rb);
                    } else {
#pragma unroll
                        for (int t = 0; t < 4; ++t)
                            iv[t] = (rb + t < N_NODES) ? invdeg[rb + t] : 0.0f;
                    }
#pragma unroll
                    for (int jj = 0; jj < 4; ++jj)
                        acc[i][jj] *= iv;
                }
            }
        }
        __syncthreads();   // before overwriting As next iteration
    }

    // epilogue: bias+relu, project to 2 classes (l and r), reduce across 16 col-lanes
    float bb[4], wl0[4], wl1[4], wr0[4], wr1[4];
#pragma unroll
    for (int jj = 0; jj < 4; ++jj) {
        int col = (w >> 1) * 64 + jj * 16 + l15;
        bb[jj]  = b1[col];
        wl0[jj] = w2l[col * 2];  wl1[jj] = w2l[col * 2 + 1];
        wr0[jj] = w2r[col * 2];  wr1[jj] = w2r[col * 2 + 1];
    }
#pragma unroll
    for (int i = 0; i < 4; ++i) {
#pragma unroll
        for (int t = 0; t < 4; ++t) {
            float s0 = 0.f, s1 = 0.f, s2 = 0.f, s3 = 0.f;
#pragma unroll
            for (int jj = 0; jj < 4; ++jj) {
                float v = fmaxf(acc[i][jj][t] + bb[jj], 0.0f);
                s0 += v * wl0[jj]; s1 += v * wl1[jj];
                s2 += v * wr0[jj]; s3 += v * wr1[jj];
            }
#pragma unroll
            for (int m = 1; m < 16; m <<= 1) {
                s0 += __shfl_xor(s0, m, 64);
                s1 += __shfl_xor(s1, m, 64);
                s2 += __shfl_xor(s2, m, 64);
                s3 += __shfl_xor(s3, m, 64);
            }
            if (l15 == 0) {
                int rl = (w & 1) * 64 + i * 16 + quad * 4 + t;
                atomicAdd(&tlr[rl][0], s0);
                atomicAdd(&tlr[rl][1], s1);
                atomicAdd(&tlr[rl][2], s2);
                atomicAdd(&tlr[rl][3], s3);
            }
        }
    }
    __syncthreads();
    if (tid < 128) {
        int row = rowbase + tid;
        if (row < N_NODES) {
            tl[row * 2 + 0] = tlr[tid][0];
            tl[row * 2 + 1] = tlr[tid][1];
            tr[row * 2 + 0] = tlr[tid][2];
            tr[row * 2 + 1] = tlr[tid][3];
        }
    }
}

// ---------- K7: fused layer-2 gather + finalize (NO atomics) ----------
__global__ void gather_out_kernel(const int* __restrict__ row_start,
                                  const int* __restrict__ csr,
                                  const float* __restrict__ tl,
                                  const float* __restrict__ tr,
                                  const float* __restrict__ invdeg,
                                  const float* __restrict__ b2,
                                  float* __restrict__ out) {
    int i = blockIdx.x * blockDim.x + threadIdx.x;
    if (i >= N_NODES) return;
    int e0 = row_start[i], e1 = row_start[i + 1];
    float a0 = 0.f, a1 = 0.f;
    for (int e = e0; e < e1; ++e) {
        int s = csr[e];
        a0 += tl[s * 2 + 0];
        a1 += tl[s * 2 + 1];
    }
    float inv = invdeg[i];
    out[i * 2 + 0] = a0 * inv + tr[i * 2 + 0] + b2[0];
    out[i * 2 + 1] = a1 * inv + tr[i * 2 + 1] + b2[1];
}

// ---------- K8: edge_index -> f32 passthrough ----------
__global__ void cast_edges_kernel(const int* __restrict__ ei,
                                  float* __restrict__ out) {
    int i = blockIdx.x * blockDim.x + threadIdx.x;
    if (i < 2 * N_EDGES) out[i] = (float)ei[i];
}

// ---------- workspace layout (bytes) ----------
//   0          degi      800000   (memset 0)
//   800000     row_start 800016   (N+1 ints)
//   1600032    cursor    800000
//   2400032    invdeg    800000
//   3200032    csr       2000000
//   5200032    tl        1600000
//   6800032    tr        1600000
//   8400032    bsum      3200
//   8403232    boff      3200
//   8406432    bfrag     196608
//   8610000    aggh      76800000  (f16, stride SX)
//   85410000   xh        76800000  (f16, stride SX)
//   end 162210000
extern "C" void kernel_launch(void* const* d_in, const int* in_sizes, int n_in,
                              void* d_out, int out_size, void* d_ws, size_t ws_size,
                              hipStream_t stream) {
    const float* x    = (const float*)d_in[0];
    const int*   ei   = (const int*)d_in[1];
    const float* w1_l = (const float*)d_in[2];
    const float* w1_r = (const float*)d_in[3];
    const float* b1   = (const float*)d_in[4];
    const float* w2_l = (const float*)d_in[5];
    const float* w2_r = (const float*)d_in[6];
    const float* b2   = (const float*)d_in[7];

    char* ws = (char*)d_ws;
    int*   degi      = (int*)(ws);
    int*   row_start = (int*)(ws + 800000);
    int*   cursor    = (int*)(ws + 1600032);
    float* invdeg    = (float*)(ws + 2400032);
    int*   csr       = (int*)(ws + 3200032);
    float* tl        = (float*)(ws + 5200032);
    float* tr        = (float*)(ws + 6800032);
    int*   bsum      = (int*)(ws + 8400032);
    int*   boff      = (int*)(ws + 8403232);
    _Float16* bfrag  = (_Float16*)(ws + 8406432);
    _Float16* aggh   = (_Float16*)(ws + 8610000);
    _Float16* xh     = (_Float16*)(ws + 85410000);

    float* out = (float*)d_out;   // f32: logits [0,400000), edges [400000,1400000)

    (void)hipMemsetAsync(degi, 0, 800000, stream);

    cast_x_kernel<<<75000, 256, 0, stream>>>(x, (__half2*)xh);
    prep_bfrag_kernel<<<48, 256, 0, stream>>>(w1_l, w1_r, bfrag);

    hist_kernel<<<(N_EDGES + 255) / 256, 256, 0, stream>>>(ei, degi);
    block_sum_kernel<<<NB, 256, 0, stream>>>(degi, bsum);
    scan_bsum_kernel<<<1, 1024, 0, stream>>>(bsum, boff, row_start);
    scan_emit_kernel<<<NB, 256, 0, stream>>>(degi, boff, row_start, cursor, invdeg);
    scatter_edges_kernel<<<(N_EDGES + 255) / 256, 256, 0, stream>>>(ei, cursor, csr);

    gather_agg_kernel<<<75000, 256, 0, stream>>>((const __half2*)xh, row_start, csr,
                                                 (__half2*)aggh);

    gemm_fused_kernel<<<(N_NODES + 127) / 128, 512, 0, stream>>>(
        xh, aggh, invdeg, bfrag, b1, w2_l, w2_r, tl, tr);

    gather_out_kernel<<<NB, 256, 0, stream>>>(row_start, csr, tl, tr, invdeg, b2, out);
    cast_edges_kernel<<<(2 * N_EDGES + 255) / 256, 256, 0, stream>>>(ei, out + 2 * N_NODES);
}

// Round 8
// 426.984 us; speedup vs baseline: 3.3434x; 1.1327x over previous
//
#include <hip/hip_runtime.h>
#include <hip/hip_bf16.h>
#include <hip/hip_fp16.h>

#define N_NODES 200000
#define N_EDGES 500000
#define F_IN    165
#define HID     256
#define SX      192   // padded f16 row stride (24 half8 segs, 16B-aligned rows)
#define NB      782   // ceil(N_NODES/256) scan blocks

typedef float    floatx4 __attribute__((ext_vector_type(4)));
typedef float    floatx4a __attribute__((ext_vector_type(4), aligned(16)));
typedef float    float4u __attribute__((ext_vector_type(4), aligned(4)));
typedef _Float16 half8   __attribute__((ext_vector_type(8)));

// ---------- K0: x (f32, stride 165) -> xh (f16 half8 segs, stride 24) ----------
__global__ void cast_x_kernel(const float* __restrict__ x, half8* __restrict__ xh8) {
    int idx = blockIdx.x * blockDim.x + threadIdx.x;   // < N*24
    int row = idx / 24;
    int p = idx - row * 24;
    int f0 = p * 8;
    const float* px = x + (long)row * F_IN + f0;
    half8 r;
    if (f0 + 8 <= F_IN) {
        float4u lo = *(const float4u*)px;
        float4u hi = *(const float4u*)(px + 4);
#pragma unroll
        for (int q = 0; q < 4; ++q) r[q] = (_Float16)lo[q];
#pragma unroll
        for (int q = 0; q < 4; ++q) r[4 + q] = (_Float16)hi[q];
    } else {
#pragma unroll
        for (int q = 0; q < 8; ++q)
            r[q] = (f0 + q < F_IN) ? (_Float16)px[q] : (_Float16)0.0f;
    }
    xh8[idx] = r;
}

// ---------- K1: dst-degree histogram ----------
__global__ void hist_kernel(const int* __restrict__ ei, int* __restrict__ degi) {
    int e = blockIdx.x * blockDim.x + threadIdx.x;
    if (e < N_EDGES) atomicAdd(&degi[ei[N_EDGES + e]], 1);
}

// ---------- K2a: per-block degree sums ----------
__global__ __launch_bounds__(256) void block_sum_kernel(const int* __restrict__ degi,
                                                        int* __restrict__ bsum) {
    __shared__ int sh[256];
    int t = threadIdx.x, i = blockIdx.x * 256 + t;
    sh[t] = (i < N_NODES) ? degi[i] : 0;
    __syncthreads();
#pragma unroll
    for (int off = 128; off > 0; off >>= 1) {
        if (t < off) sh[t] += sh[t + off];
        __syncthreads();
    }
    if (t == 0) bsum[blockIdx.x] = sh[0];
}

// ---------- K2b: scan the 782 block sums (1 block) ----------
__global__ __launch_bounds__(1024) void scan_bsum_kernel(const int* __restrict__ bsum,
                                                         int* __restrict__ boff,
                                                         int* __restrict__ row_start) {
    __shared__ int sh[1024];
    int t = threadIdx.x;
    int v = (t < NB) ? bsum[t] : 0;
    sh[t] = v;
    __syncthreads();
    for (int off = 1; off < 1024; off <<= 1) {
        int u = (t >= off) ? sh[t - off] : 0;
        __syncthreads();
        sh[t] += u;
        __syncthreads();
    }
    if (t < NB) boff[t] = sh[t] - v;               // exclusive
    if (t == 1023) row_start[N_NODES] = sh[1023];  // total = E
}

// ---------- K2c: emit row_start / cursor / invdeg ----------
__global__ __launch_bounds__(256) void scan_emit_kernel(const int* __restrict__ degi,
                                                        const int* __restrict__ boff,
                                                        int* __restrict__ row_start,
                                                        int* __restrict__ cursor,
                                                        float* __restrict__ invdeg) {
    __shared__ int sh[256];
    int t = threadIdx.x, i = blockIdx.x * 256 + t;
    int d = (i < N_NODES) ? degi[i] : 0;
    sh[t] = d;
    __syncthreads();
#pragma unroll
    for (int off = 1; off < 256; off <<= 1) {
        int u = (t >= off) ? sh[t - off] : 0;
        __syncthreads();
        sh[t] += u;
        __syncthreads();
    }
    if (i < N_NODES) {
        int row = boff[blockIdx.x] + sh[t] - d;    // exclusive scan value
        row_start[i] = row;
        cursor[i] = row;
        invdeg[i] = 1.0f / fmaxf((float)d, 1.0f);
    }
}

// ---------- K3: bucket edges into CSR ----------
__global__ void scatter_edges_kernel(const int* __restrict__ ei,
                                     int* __restrict__ cursor,
                                     int* __restrict__ csr) {
    int e = blockIdx.x * blockDim.x + threadIdx.x;
    if (e >= N_EDGES) return;
    int s = ei[e];
    int d = ei[N_EDGES + e];
    int pos = atomicAdd(&cursor[d], 1);
    csr[pos] = s;
}

// ---------- K4: gather-aggregate (NO atomics): aggh[n] = sum xh[src] ----------
// thread (n, p<24): one half8 (16B) load per edge; f16 pk-add accumulation
// (deg~2.5 unit-scale values — abs err ~0.01 vs threshold 3993); 2-deep unroll
// for memory-level parallelism.
__global__ void gather_agg_kernel(const half8* __restrict__ xh8,
                                  const int* __restrict__ row_start,
                                  const int* __restrict__ csr,
                                  half8* __restrict__ aggh8) {
    int idx = blockIdx.x * blockDim.x + threadIdx.x;   // < N*24
    int n = idx / 24;
    int p = idx - n * 24;
    int e0 = row_start[n], e1 = row_start[n + 1];
    half8 acc = {0, 0, 0, 0, 0, 0, 0, 0};
    half8 acc2 = {0, 0, 0, 0, 0, 0, 0, 0};
    int e = e0;
    for (; e + 2 <= e1; e += 2) {
        int s0 = csr[e], s1 = csr[e + 1];
        half8 v0 = xh8[(long)s0 * 24 + p];
        half8 v1 = xh8[(long)s1 * 24 + p];
        acc += v0;
        acc2 += v1;
    }
    if (e < e1) acc += xh8[(long)csr[e] * 24 + p];
    aggh8[idx] = acc + acc2;
}

// ---------- K5: pack [w1_l | w1_r] (f16) into MFMA B-fragment order ----------
__global__ void prep_bfrag_kernel(const float* __restrict__ w1l,
                                  const float* __restrict__ w1r,
                                  _Float16* __restrict__ bfrag) {
    int gid = blockIdx.x * blockDim.x + threadIdx.x;
    if (gid >= 12 * 16 * 64) return;
    int lane = gid & 63;
    int j = (gid >> 6) & 15;
    int c = gid >> 10;
    int quad = lane >> 4, n = lane & 15;
    const float* w = (c < 6) ? w1l : w1r;
    int kb = (c < 6 ? c : c - 6) * 32;
    int col = j * 16 + n;
    half8 r;
#pragma unroll
    for (int q = 0; q < 8; ++q) {
        int k = kb + quad * 8 + q;
        r[q] = (_Float16)((k < F_IN) ? w[k * HID + col] : 0.0f);
    }
    *(half8*)(bfrag + gid * 8) = r;
}

// ---------- K6: fused MFMA GEMM + invdeg + bias + relu + layer-2 projection ----------
// A-tile staged through LDS via global_load_lds width=16 (each A byte enters CU once).
// XOR-swizzled LDS layout: slot(r,q) = r*4 + (q ^ ((r>>1)&3)); DMA stays lane-contiguous.
__global__ __launch_bounds__(512, 2) void gemm_fused_kernel(
        const _Float16* __restrict__ xh, const _Float16* __restrict__ aggh,
        const float* __restrict__ invdeg, const _Float16* __restrict__ bfrag,
        const float* __restrict__ b1,
        const float* __restrict__ w2l, const float* __restrict__ w2r,
        float* __restrict__ tl, float* __restrict__ tr) {
    __shared__ __attribute__((aligned(16))) _Float16 As[2][128 * 32];  // 2 x 8KB
    __shared__ float tlr[128][4];
    const int tid = threadIdx.x;
    const int w = tid >> 6, lane = tid & 63;
    const int quad = lane >> 4, l15 = lane & 15;
    const int rowbase = blockIdx.x * 128;
    const int mrow0 = rowbase + (w & 1) * 64;
    const int rhalf = (w & 1) * 64;
    const int jbase = (w >> 1) * 4;

    ((float*)tlr)[tid < 512 ? tid : 0] = 0.0f;

    const int srow_l = tid >> 2;
    const int sseg = (tid & 3) ^ ((srow_l >> 1) & 3);
    int srow = rowbase + srow_l;
    if (srow >= N_NODES) srow = N_NODES - 1;
    const long sgoff = (long)srow * SX + sseg * 8;

    floatx4 acc[4][4];
#pragma unroll
    for (int i = 0; i < 4; ++i)
#pragma unroll
        for (int jj = 0; jj < 4; ++jj)
            acc[i][jj] = (floatx4){0.f, 0.f, 0.f, 0.f};

    __syncthreads();

#pragma unroll 1
    for (int it = 0; it < 6; ++it) {
#pragma unroll
        for (int u = 0; u < 2; ++u) {
            const int cc = it * 2 + u;
            const _Float16* __restrict__ src = (cc < 6) ? aggh : xh;
            const int kb = (cc < 6 ? cc : cc - 6) * 32;
            const _Float16* gp = src + sgoff + kb;
            char* dst = (char*)(&As[u][0]) + (tid & ~63) * 16;  // wave-uniform base
            __builtin_amdgcn_global_load_lds(
                (const __attribute__((address_space(1))) void*)gp,
                (__attribute__((address_space(3))) void*)dst, 16, 0, 0);
        }
        __syncthreads();   // drains the DMA (vmcnt) + orders LDS

#pragma unroll
        for (int u = 0; u < 2; ++u) {
            const int cc = it * 2 + u;
            half8 a[4], b[4];
#pragma unroll
            for (int i = 0; i < 4; ++i) {
                int r = rhalf + i * 16 + l15;
                int slot = r * 4 + (quad ^ ((r >> 1) & 3));
                a[i] = *(const half8*)(&As[u][slot * 8]);
            }
#pragma unroll
            for (int jj = 0; jj < 4; ++jj)
                b[jj] = *(const half8*)(bfrag + (((cc * 16) + jbase + jj) * 64 + lane) * 8);
#pragma unroll
            for (int i = 0; i < 4; ++i)
#pragma unroll
                for (int jj = 0; jj < 4; ++jj)
                    acc[i][jj] = __builtin_amdgcn_mfma_f32_16x16x32_f16(a[i], b[jj], acc[i][jj], 0, 0, 0);

            if (cc == 5) {   // agg phase done: scale accumulator rows by invdeg
#pragma unroll
                for (int i = 0; i < 4; ++i) {
                    int rb = mrow0 + i * 16 + quad * 4;
                    floatx4 iv;
                    if (rb + 3 < N_NODES) {
                        iv = *(const floatx4a*)(invdeg + rb);
                    } else {
#pragma unroll
                        for (int t = 0; t < 4; ++t)
                            iv[t] = (rb + t < N_NODES) ? invdeg[rb + t] : 0.0f;
                    }
#pragma unroll
                    for (int jj = 0; jj < 4; ++jj)
                        acc[i][jj] *= iv;
                }
            }
        }
        __syncthreads();   // before overwriting As next iteration
    }

    float bb[4], wl0[4], wl1[4], wr0[4], wr1[4];
#pragma unroll
    for (int jj = 0; jj < 4; ++jj) {
        int col = (w >> 1) * 64 + jj * 16 + l15;
        bb[jj]  = b1[col];
        wl0[jj] = w2l[col * 2];  wl1[jj] = w2l[col * 2 + 1];
        wr0[jj] = w2r[col * 2];  wr1[jj] = w2r[col * 2 + 1];
    }
#pragma unroll
    for (int i = 0; i < 4; ++i) {
#pragma unroll
        for (int t = 0; t < 4; ++t) {
            float s0 = 0.f, s1 = 0.f, s2 = 0.f, s3 = 0.f;
#pragma unroll
            for (int jj = 0; jj < 4; ++jj) {
                float v = fmaxf(acc[i][jj][t] + bb[jj], 0.0f);
                s0 += v * wl0[jj]; s1 += v * wl1[jj];
                s2 += v * wr0[jj]; s3 += v * wr1[jj];
            }
#pragma unroll
            for (int m = 1; m < 16; m <<= 1) {
                s0 += __shfl_xor(s0, m, 64);
                s1 += __shfl_xor(s1, m, 64);
                s2 += __shfl_xor(s2, m, 64);
                s3 += __shfl_xor(s3, m, 64);
            }
            if (l15 == 0) {
                int rl = (w & 1) * 64 + i * 16 + quad * 4 + t;
                atomicAdd(&tlr[rl][0], s0);
                atomicAdd(&tlr[rl][1], s1);
                atomicAdd(&tlr[rl][2], s2);
                atomicAdd(&tlr[rl][3], s3);
            }
        }
    }
    __syncthreads();
    if (tid < 128) {
        int row = rowbase + tid;
        if (row < N_NODES) {
            tl[row * 2 + 0] = tlr[tid][0];
            tl[row * 2 + 1] = tlr[tid][1];
            tr[row * 2 + 0] = tlr[tid][2];
            tr[row * 2 + 1] = tlr[tid][3];
        }
    }
}

// ---------- K7: fused layer-2 gather + finalize (NO atomics) ----------
__global__ void gather_out_kernel(const int* __restrict__ row_start,
                                  const int* __restrict__ csr,
                                  const float* __restrict__ tl,
                                  const float* __restrict__ tr,
                                  const float* __restrict__ invdeg,
                                  const float* __restrict__ b2,
                                  float* __restrict__ out) {
    int i = blockIdx.x * blockDim.x + threadIdx.x;
    if (i >= N_NODES) return;
    int e0 = row_start[i], e1 = row_start[i + 1];
    float a0 = 0.f, a1 = 0.f;
    for (int e = e0; e < e1; ++e) {
        int s = csr[e];
        a0 += tl[s * 2 + 0];
        a1 += tl[s * 2 + 1];
    }
    float inv = invdeg[i];
    out[i * 2 + 0] = a0 * inv + tr[i * 2 + 0] + b2[0];
    out[i * 2 + 1] = a1 * inv + tr[i * 2 + 1] + b2[1];
}

// ---------- K8: edge_index -> f32 passthrough ----------
__global__ void cast_edges_kernel(const int* __restrict__ ei,
                                  float* __restrict__ out) {
    int i = blockIdx.x * blockDim.x + threadIdx.x;
    if (i < 2 * N_EDGES) out[i] = (float)ei[i];
}

// ---------- workspace layout (bytes) ----------
//   0          degi      800000   (memset 0)
//   800000     row_start 800016   (N+1 ints)
//   1600032    cursor    800000
//   2400032    invdeg    800000
//   3200032    csr       2000000
//   5200032    tl        1600000
//   6800032    tr        1600000
//   8400032    bsum      3200
//   8403232    boff      3200
//   8406432    bfrag     196608
//   8610000    aggh      76800000  (f16, stride SX)
//   85410000   xh        76800000  (f16, stride SX)
extern "C" void kernel_launch(void* const* d_in, const int* in_sizes, int n_in,
                              void* d_out, int out_size, void* d_ws, size_t ws_size,
                              hipStream_t stream) {
    const float* x    = (const float*)d_in[0];
    const int*   ei   = (const int*)d_in[1];
    const float* w1_l = (const float*)d_in[2];
    const float* w1_r = (const float*)d_in[3];
    const float* b1   = (const float*)d_in[4];
    const float* w2_l = (const float*)d_in[5];
    const float* w2_r = (const float*)d_in[6];
    const float* b2   = (const float*)d_in[7];

    char* ws = (char*)d_ws;
    int*   degi      = (int*)(ws);
    int*   row_start = (int*)(ws + 800000);
    int*   cursor    = (int*)(ws + 1600032);
    float* invdeg    = (float*)(ws + 2400032);
    int*   csr       = (int*)(ws + 3200032);
    float* tl        = (float*)(ws + 5200032);
    float* tr        = (float*)(ws + 6800032);
    int*   bsum      = (int*)(ws + 8400032);
    int*   boff      = (int*)(ws + 8403232);
    _Float16* bfrag  = (_Float16*)(ws + 8406432);
    _Float16* aggh   = (_Float16*)(ws + 8610000);
    _Float16* xh     = (_Float16*)(ws + 85410000);

    float* out = (float*)d_out;   // f32: logits [0,400000), edges [400000,1400000)

    (void)hipMemsetAsync(degi, 0, 800000, stream);

    cast_x_kernel<<<(N_NODES * 24) / 256, 256, 0, stream>>>(x, (half8*)xh);
    prep_bfrag_kernel<<<48, 256, 0, stream>>>(w1_l, w1_r, bfrag);

    hist_kernel<<<(N_EDGES + 255) / 256, 256, 0, stream>>>(ei, degi);
    block_sum_kernel<<<NB, 256, 0, stream>>>(degi, bsum);
    scan_bsum_kernel<<<1, 1024, 0, stream>>>(bsum, boff, row_start);
    scan_emit_kernel<<<NB, 256, 0, stream>>>(degi, boff, row_start, cursor, invdeg);
    scatter_edges_kernel<<<(N_EDGES + 255) / 256, 256, 0, stream>>>(ei, cursor, csr);

    gather_agg_kernel<<<(N_NODES * 24) / 256, 256, 0, stream>>>(
        (const half8*)xh, row_start, csr, (half8*)aggh);

    gemm_fused_kernel<<<(N_NODES + 127) / 128, 512, 0, stream>>>(
        xh, aggh, invdeg, bfrag, b1, w2_l, w2_r, tl, tr);

    gather_out_kernel<<<NB, 256, 0, stream>>>(row_start, csr, tl, tr, invdeg, b2, out);
    cast_edges_kernel<<<(2 * N_EDGES + 255) / 256, 256, 0, stream>>>(ei, out + 2 * N_NODES);
}